// Round 5
// baseline (182.830 us; speedup 1.0000x reference)
//
#include <hip/hip_runtime.h>

// Differentiable gaussian renderer, separable-splat formulation.
//
//   w(px,py) = op * exp(-0.5*((px-u)^2+(py-v)^2)/var)
//            = [exp2(ke*(py-v)^2)] * [exp2(ke*(px-u)^2)],  ke = -0.5*log2(e)/var
//
// => per pose: C[y][n] = sum_g A[y][g] * B[g][n],  n = c*128+x
//    A[y][g]       = fy_g(y),  B[g][c*128+x] = (op*color_c)_g * fx_g(x)
//    (c=3: color=1 -> denominator)
//
// R4 -> R5 (render ~45us, insensitive to param-traffic cut -> attack the rest):
//  * full-height blocks: grid = 128 splits x 2 poses, block = [128y x 512n]
//    over 512 gaussians (8 chunks): kills fx y-half duplication (50M->33.5M
//    exps), halves barriers (16).
//  * [128m x 64n] wave tiles (2 ksets x 8 wn, acc=128 VGPR; 4 waves/SIMD ->
//    512 VGPR budget): frag LDS traffic -25%.
//  * bf16 partials (exponent range of fp32 -> no R2 subnormal failure):
//    render writes + reduce reads halve to 16.8 MB each.

#define H_IMG 128
#define W_IMG 128
#define FX_C 120.0f
#define FY_C 120.0f
#define CX_C 64.0f
#define CY_C 64.0f
#define NG 65536
#define SLAB 512          // gaussians per block
#define KSPLIT 128        // NG / SLAB
#define NCHUNK 8          // SLAB / 64
#define APAD 72           // 64 + 8 bf16 pad: row stride 144B (16B aligned)
#define NEG_HALF_LOG2E -0.72134752044448170f
#define EPS_TOT 1.6e-7f   // n_chunks(16) * 1e-8

#if __has_builtin(__builtin_amdgcn_exp2f)
#define EXP2(x) __builtin_amdgcn_exp2f(x)
#else
#define EXP2(x) exp2f(x)
#endif

typedef __attribute__((ext_vector_type(8))) short short8;   // 8 bf16 = 4 VGPRs
typedef __attribute__((ext_vector_type(4))) float f32x4;    // MFMA acc

// pack two f32 -> two bf16 (round-half-up) in 3 VALU ops via v_perm_b32.
__device__ __forceinline__ unsigned bfpk2(float a, float b) {
    return __builtin_amdgcn_perm(__float_as_uint(b) + 0x8000u,
                                 __float_as_uint(a) + 0x8000u,
                                 0x07060302u);
}
__device__ __forceinline__ ushort bf16u(float v) {
    return (ushort)((__float_as_uint(v) + 0x8000u) >> 16);
}

__global__ void zero_accum_kernel(float* __restrict__ p) {
    p[blockIdx.x * 256 + threadIdx.x] = 0.0f;   // grid 512 x 256 = 131072 floats
}

// grid dim3(128, 2): blockIdx.x = K-split, blockIdx.y = pose
template <bool STORE>
__global__ __launch_bounds__(1024) void render_kernel(
    const float* __restrict__ gpos, const float* __restrict__ gcol,
    const float* __restrict__ gopa, const float* __restrict__ gscl,
    const float* __restrict__ qvec, const float* __restrict__ tvec,
    float* __restrict__ accum,                 // ATOMIC path: [2][128 y][512 n] fp32
    ushort* __restrict__ pbuf)                 // STORE path: [2][128 s][128 y][512 n] bf16
{
    __shared__ ushort A_lds[H_IMG][APAD];            // fy,  [y][kc]      18 KB
    __shared__ ushort B_lds[512][APAD];              // B^T, [n][kc]      72 KB (merge scratch)
    __shared__ float u_s[SLAB], v_s[SLAB], ke_s[SLAB];
    __shared__ float wc_s[4][SLAB];                  // op*{r,g,b,1}

    const int split = blockIdx.x;                    // 0..127
    const int pose  = blockIdx.y;                    // 0..1
    const int tid   = threadIdx.x;                   // 0..1023

    // ---- camera: quaternion -> R ----
    float q0 = qvec[pose*4+0], q1 = qvec[pose*4+1], q2 = qvec[pose*4+2], q3 = qvec[pose*4+3];
    float rn = rsqrtf(q0*q0 + q1*q1 + q2*q2 + q3*q3);
    float qw = q0*rn, qx = q1*rn, qy = q2*rn, qz = q3*rn;
    float r00 = 1.0f-2.0f*(qy*qy+qz*qz), r01 = 2.0f*(qx*qy-qz*qw), r02 = 2.0f*(qx*qz+qy*qw);
    float r10 = 2.0f*(qx*qy+qz*qw), r11 = 1.0f-2.0f*(qx*qx+qz*qz), r12 = 2.0f*(qy*qz-qx*qw);
    float r20 = 2.0f*(qx*qz-qy*qw), r21 = 2.0f*(qy*qz+qx*qw), r22 = 1.0f-2.0f*(qx*qx+qy*qy);
    float tx = tvec[pose*3+0], ty = tvec[pose*3+1], tz = tvec[pose*3+2];

    // ---- per-slab gaussian params, staged once (512 g, 1/thread) ----
    if (tid < SLAB) {
        int g = split*SLAB + tid;
        float p0 = gpos[g*3+0], p1 = gpos[g*3+1], p2 = gpos[g*3+2];
        float cxm = r00*p0 + r01*p1 + r02*p2 + tx;
        float cym = r10*p0 + r11*p1 + r12*p2 + ty;
        float czm = r20*p0 + r21*p1 + r22*p2 + tz;
        float iz  = 1.0f / czm;
        u_s[tid] = cxm*iz*FX_C + CX_C;
        v_s[tid] = cym*iz*FY_C + CY_C;
        float s  = gscl[g];
        ke_s[tid] = NEG_HALF_LOG2E / (s*s);
        float og = gopa[g];
        wc_s[0][tid] = og * gcol[g*3+0];
        wc_s[1][tid] = og * gcol[g*3+1];
        wc_s[2][tid] = og * gcol[g*3+2];
        wc_s[3][tid] = og;
    }
    __syncthreads();

    const int lane = tid & 63;
    const int wave = tid >> 6;            // 0..15
    const int kset = wave >> 3;           // 0: k 0..31 of chunk, 1: k 32..63
    const int wn8  = wave & 7;            // n band: [wn8*64, wn8*64+64)

    // staging roles: threads 0..511 stage B (4g x 4x), 512..1023 stage A (4g x 4y)
    const bool isB = (tid < 512);
    const int st   = tid & 511;
    const int g4   = (st & 15) << 2;      // 0,4,..,60
    const int grp  = st >> 4;             // 0..31 -> 4 rows grp*4..grp*4+3

    // MFMA frag addressing (verified layouts for 16x16x32 bf16)
    const int frow = lane & 15;
    const int kcol = kset*32 + ((lane >> 4) << 3);   // k = kset*32 + quad*8 + j

    f32x4 acc[8][4] = {};   // [mt][nt]: m = mt*16 + quad*4 + r, n = wn8*64 + nt*16 + (lane&15)

    for (int ch = 0; ch < NCHUNK; ++ch) {
        const int gb = (ch << 6) + g4;
        const float4 kv = *(const float4*)&ke_s[gb];
        if (isB) {
            // ---- fx, channel-weighted -> B_lds[c*128 + x][g4..g4+3], x = grp*4+xi ----
            const float4 uv = *(const float4*)&u_s[gb];
            float e[4][4];
            #pragma unroll
            for (int xi = 0; xi < 4; ++xi) {
                const float xf = (float)(grp*4 + xi);
                float d;
                d = xf - uv.x; e[xi][0] = EXP2(kv.x*d*d);
                d = xf - uv.y; e[xi][1] = EXP2(kv.y*d*d);
                d = xf - uv.z; e[xi][2] = EXP2(kv.z*d*d);
                d = xf - uv.w; e[xi][3] = EXP2(kv.w*d*d);
            }
            #pragma unroll
            for (int c = 0; c < 4; ++c) {
                const float4 wv = *(const float4*)&wc_s[c][gb];
                #pragma unroll
                for (int xi = 0; xi < 4; ++xi) {
                    uint2 pk;
                    pk.x = bfpk2(e[xi][0]*wv.x, e[xi][1]*wv.y);
                    pk.y = bfpk2(e[xi][2]*wv.z, e[xi][3]*wv.w);
                    *(uint2*)&B_lds[(c << 7) + grp*4 + xi][g4] = pk;
                }
            }
        } else {
            // ---- fy -> A_lds[y][g4..g4+3], y = grp*4+yi ----
            const float4 vv = *(const float4*)&v_s[gb];
            #pragma unroll
            for (int yi = 0; yi < 4; ++yi) {
                const float yf = (float)(grp*4 + yi);
                float d, f0, f1, f2, f3;
                d = yf - vv.x; f0 = EXP2(kv.x*d*d);
                d = yf - vv.y; f1 = EXP2(kv.y*d*d);
                d = yf - vv.z; f2 = EXP2(kv.z*d*d);
                d = yf - vv.w; f3 = EXP2(kv.w*d*d);
                uint2 pk;
                pk.x = bfpk2(f0, f1); pk.y = bfpk2(f2, f3);
                *(uint2*)&A_lds[grp*4 + yi][g4] = pk;
            }
        }
        __syncthreads();
        // ---- MFMA: one K=32 step per wave (split-K across wave sets) ----
        {
            short8 a[8], b[4];
            #pragma unroll
            for (int mt = 0; mt < 8; ++mt)
                a[mt] = *(const short8*)&A_lds[mt*16 + frow][kcol];
            #pragma unroll
            for (int nt = 0; nt < 4; ++nt)
                b[nt] = *(const short8*)&B_lds[wn8*64 + nt*16 + frow][kcol];
            #pragma unroll
            for (int mt = 0; mt < 8; ++mt)
                #pragma unroll
                for (int nt = 0; nt < 4; ++nt)
                    acc[mt][nt] = __builtin_amdgcn_mfma_f32_16x16x32_bf16(a[mt], b[nt], acc[mt][nt], 0, 0, 0);
        }
        __syncthreads();
    }

    // ---- split-K merge: kset1 -> kset0 via B_lds scratch (64 KB/round, 4 rounds) ----
    f32x4* scr = (f32x4*)&B_lds[0][0];
    #pragma unroll
    for (int r = 0; r < 4; ++r) {
        if (kset == 1) {
            #pragma unroll
            for (int m2 = 0; m2 < 2; ++m2)
                #pragma unroll
                for (int nt = 0; nt < 4; ++nt)
                    scr[(((wn8*2 + m2)*4 + nt) << 6) + lane] = acc[r*2 + m2][nt];
        }
        __syncthreads();
        if (kset == 0) {
            #pragma unroll
            for (int m2 = 0; m2 < 2; ++m2)
                #pragma unroll
                for (int nt = 0; nt < 4; ++nt)
                    acc[r*2 + m2][nt] += scr[(((wn8*2 + m2)*4 + nt) << 6) + lane];
        }
        __syncthreads();
    }

    // ---- epilogue (kset0 waves): [128y x 64n] per wave ----
    if (kset == 0) {
        const int q4 = (lane >> 4) << 2;          // 0,4,8,12
        const int n0 = wn8*64 + (lane & 15);
        if (STORE) {
            ushort* bp = pbuf + ((size_t)(pose*KSPLIT + split) * H_IMG) * 512 + n0;
            #pragma unroll
            for (int mt = 0; mt < 8; ++mt)
                #pragma unroll
                for (int nt = 0; nt < 4; ++nt)
                    #pragma unroll
                    for (int r = 0; r < 4; ++r)
                        bp[(size_t)(mt*16 + q4 + r)*512 + nt*16] = bf16u(acc[mt][nt][r]);
        } else {
            float* bp = accum + ((size_t)(pose*H_IMG) * 512) + n0;
            #pragma unroll
            for (int mt = 0; mt < 8; ++mt)
                #pragma unroll
                for (int nt = 0; nt < 4; ++nt)
                    #pragma unroll
                    for (int r = 0; r < 4; ++r)
                        atomicAdd(bp + (size_t)(mt*16 + q4 + r)*512 + nt*16, acc[mt][nt][r]);
        }
    }
}

// STORE path: sum the 128 split partials (bf16), normalize, tiled output.
// grid 256 = (pose, y); 1024 threads = (s-half sg, n 0..511).
__global__ __launch_bounds__(1024) void reduce_norm_kernel(
    const ushort* __restrict__ pbuf, float* __restrict__ out)
{
    __shared__ float red[2][512];
    const int b  = blockIdx.x;
    const int p  = b >> 7;
    const int y  = b & 127;
    const int t  = threadIdx.x;
    const int sg = t >> 9;               // 0/1: splits [sg*64, sg*64+64)
    const int n  = t & 511;

    const ushort* base = pbuf + ((size_t)(p*KSPLIT + sg*64) * H_IMG + y) * 512 + n;
    float s = 0.0f;
    #pragma unroll 8
    for (int i = 0; i < 64; ++i) {
        unsigned us = base[(size_t)i * (H_IMG*512)];
        s += __uint_as_float(us << 16);
    }
    red[sg][n] = s;
    __syncthreads();

    if (t < 384) {
        const int c = t >> 7, x = t & 127;
        float den = red[0][384 + x] + red[1][384 + x];
        float num = red[0][t]       + red[1][t];
        float inv = 1.0f / (den + EPS_TOT);
        // output: [pose*16 + tile][3][32][32], tile = y>>3, q = (y&7)*128 + x
        int tt = y >> 3;
        int q  = ((y & 7) << 7) + x;
        out[(size_t)((p*16 + tt)*3 + c) * 1024 + q] = num * inv;
    }
}

// ATOMIC fallback: img = num/(den+eps), tiled output layout.
__global__ void normalize_kernel(const float* __restrict__ acc, float* __restrict__ out) {
    int idx = blockIdx.x * 256 + threadIdx.x;   // 0..32767 : (pose, y, x)
    int x = idx & 127;
    int y = (idx >> 7) & 127;
    int p = idx >> 14;
    const float* base = acc + (size_t)(p*128 + y) * 512;
    float inv = 1.0f / (base[384 + x] + EPS_TOT);
    int t = y >> 3;
    int q = ((y & 7) << 7) + x;
    float* ob = out + (size_t)((p*16 + t)*3) * 1024 + q;
    ob[0]    = base[x]       * inv;
    ob[1024] = base[128 + x] * inv;
    ob[2048] = base[256 + x] * inv;
}

extern "C" void kernel_launch(void* const* d_in, const int* in_sizes, int n_in,
                              void* d_out, int out_size, void* d_ws, size_t ws_size,
                              hipStream_t stream) {
    const float* gpos = (const float*)d_in[0];   // [65536,3]
    const float* gcol = (const float*)d_in[1];   // [65536,3]
    const float* gopa = (const float*)d_in[2];   // [65536,1]
    const float* gscl = (const float*)d_in[3];   // [65536,1]
    const float* qv   = (const float*)d_in[4];   // [2,4]
    const float* tv   = (const float*)d_in[5];   // [2,3]
    float* out = (float*)d_out;                  // [32,3,32,32] fp32

    // bf16 partials: 2 poses * 128 splits * 128 y * 512 n * 2B = 33,554,432 B
    const size_t need = (size_t)2 * KSPLIT * H_IMG * 512 * sizeof(ushort);

    if (ws_size >= need) {
        ushort* pbuf = (ushort*)d_ws;
        render_kernel<true><<<dim3(KSPLIT, 2), dim3(1024), 0, stream>>>(
            gpos, gcol, gopa, gscl, qv, tv, nullptr, pbuf);
        reduce_norm_kernel<<<dim3(256), dim3(1024), 0, stream>>>(pbuf, out);
    } else {
        float* acc = (float*)d_ws;               // 512 KB fp32 accumulator
        zero_accum_kernel<<<dim3(512), dim3(256), 0, stream>>>(acc);
        render_kernel<false><<<dim3(KSPLIT, 2), dim3(1024), 0, stream>>>(
            gpos, gcol, gopa, gscl, qv, tv, acc, nullptr);
        normalize_kernel<<<dim3(128), dim3(256), 0, stream>>>(acc, out);
    }
}

// Round 6
// 108.363 us; speedup vs baseline: 1.6872x; 1.6872x over previous
//
#include <hip/hip_runtime.h>

// Differentiable gaussian renderer, separable-splat formulation.
//
//   w(px,py) = op * exp(-0.5*((px-u)^2+(py-v)^2)/var)
//            = [exp2(ke*(py-v)^2)] * [exp2(ke*(px-u)^2)],  ke = -0.5*log2(e)/var
//
// => per pose: C[y][n] = sum_g A[y][g] * B[g][n],  n = c*128+x
//    A[y][g]       = fy_g(y),  B[g][c*128+x] = (op*color_c)_g * fx_g(x)
//    (c=3: color=1 -> denominator)
//
// R5 -> R6: R5's acc[8][4]=128 fp32/lane spilled to scratch (VGPR_Count=64,
// FETCH 132MB / WRITE 352MB of spill traffic -> 104us). Fix: [64m x 64n]
// wave tiles (16 waves = 2 m-bands x 8 n-bands), acc[4][4]=64 fp32, full
// K=64 per wave (no split-K merge), __launch_bounds__(1024, 4) -> 128 VGPR
// budget, no spill. Keeps R5's full-height blocks (no fx dup) + bf16
// partials (validated in R5: absmax 0.0078).

#define H_IMG 128
#define W_IMG 128
#define FX_C 120.0f
#define FY_C 120.0f
#define CX_C 64.0f
#define CY_C 64.0f
#define NG 65536
#define SLAB 512          // gaussians per block
#define KSPLIT 128        // NG / SLAB
#define NCHUNK 8          // SLAB / 64
#define APAD 72           // 64 + 8 bf16 pad: row stride 144B (16B aligned)
#define NEG_HALF_LOG2E -0.72134752044448170f
#define EPS_TOT 1.6e-7f   // n_chunks(16) * 1e-8

#if __has_builtin(__builtin_amdgcn_exp2f)
#define EXP2(x) __builtin_amdgcn_exp2f(x)
#else
#define EXP2(x) exp2f(x)
#endif

typedef __attribute__((ext_vector_type(8))) short short8;   // 8 bf16 = 4 VGPRs
typedef __attribute__((ext_vector_type(4))) float f32x4;    // MFMA acc

// pack two f32 -> two bf16 (round-half-up) in 3 VALU ops via v_perm_b32.
__device__ __forceinline__ unsigned bfpk2(float a, float b) {
    return __builtin_amdgcn_perm(__float_as_uint(b) + 0x8000u,
                                 __float_as_uint(a) + 0x8000u,
                                 0x07060302u);
}
__device__ __forceinline__ ushort bf16u(float v) {
    return (ushort)((__float_as_uint(v) + 0x8000u) >> 16);
}

__global__ void zero_accum_kernel(float* __restrict__ p) {
    p[blockIdx.x * 256 + threadIdx.x] = 0.0f;   // grid 512 x 256 = 131072 floats
}

// grid dim3(128, 2): blockIdx.x = K-split, blockIdx.y = pose
template <bool STORE>
__global__ __launch_bounds__(1024, 4) void render_kernel(
    const float* __restrict__ gpos, const float* __restrict__ gcol,
    const float* __restrict__ gopa, const float* __restrict__ gscl,
    const float* __restrict__ qvec, const float* __restrict__ tvec,
    float* __restrict__ accum,                 // ATOMIC path: [2][128 y][512 n] fp32
    ushort* __restrict__ pbuf)                 // STORE path: [2][128 s][128 y][512 n] bf16
{
    __shared__ ushort A_lds[H_IMG][APAD];            // fy,  [y][kc]      18 KB
    __shared__ ushort B_lds[512][APAD];              // B^T, [n][kc]      72 KB
    __shared__ float u_s[SLAB], v_s[SLAB], ke_s[SLAB];
    __shared__ float wc_s[4][SLAB];                  // op*{r,g,b,1}

    const int split = blockIdx.x;                    // 0..127
    const int pose  = blockIdx.y;                    // 0..1
    const int tid   = threadIdx.x;                   // 0..1023

    // ---- camera: quaternion -> R ----
    float q0 = qvec[pose*4+0], q1 = qvec[pose*4+1], q2 = qvec[pose*4+2], q3 = qvec[pose*4+3];
    float rn = rsqrtf(q0*q0 + q1*q1 + q2*q2 + q3*q3);
    float qw = q0*rn, qx = q1*rn, qy = q2*rn, qz = q3*rn;
    float r00 = 1.0f-2.0f*(qy*qy+qz*qz), r01 = 2.0f*(qx*qy-qz*qw), r02 = 2.0f*(qx*qz+qy*qw);
    float r10 = 2.0f*(qx*qy+qz*qw), r11 = 1.0f-2.0f*(qx*qx+qz*qz), r12 = 2.0f*(qy*qz-qx*qw);
    float r20 = 2.0f*(qx*qz-qy*qw), r21 = 2.0f*(qy*qz+qx*qw), r22 = 1.0f-2.0f*(qx*qx+qy*qy);
    float tx = tvec[pose*3+0], ty = tvec[pose*3+1], tz = tvec[pose*3+2];

    // ---- per-slab gaussian params, staged once (512 g, 1/thread) ----
    if (tid < SLAB) {
        int g = split*SLAB + tid;
        float p0 = gpos[g*3+0], p1 = gpos[g*3+1], p2 = gpos[g*3+2];
        float cxm = r00*p0 + r01*p1 + r02*p2 + tx;
        float cym = r10*p0 + r11*p1 + r12*p2 + ty;
        float czm = r20*p0 + r21*p1 + r22*p2 + tz;
        float iz  = 1.0f / czm;
        u_s[tid] = cxm*iz*FX_C + CX_C;
        v_s[tid] = cym*iz*FY_C + CY_C;
        float s  = gscl[g];
        ke_s[tid] = NEG_HALF_LOG2E / (s*s);
        float og = gopa[g];
        wc_s[0][tid] = og * gcol[g*3+0];
        wc_s[1][tid] = og * gcol[g*3+1];
        wc_s[2][tid] = og * gcol[g*3+2];
        wc_s[3][tid] = og;
    }
    __syncthreads();

    const int lane = tid & 63;
    const int wave = tid >> 6;            // 0..15
    const int wm   = wave >> 3;           // m band: [wm*64, wm*64+64)
    const int wn8  = wave & 7;            // n band: [wn8*64, wn8*64+64)

    // staging roles: threads 0..511 stage B (4g x 4x), 512..1023 stage A (4g x 4y)
    const bool isB = (tid < 512);
    const int st   = tid & 511;
    const int g4   = (st & 15) << 2;      // 0,4,..,60
    const int grp  = st >> 4;             // 0..31 -> 4 rows grp*4..grp*4+3

    // MFMA frag addressing (verified layouts for 16x16x32 bf16)
    const int frow = lane & 15;
    const int kqd  = (lane >> 4) << 3;    // k = ks*32 + quad*8 + j

    f32x4 acc[4][4] = {};  // [mt][nt]: m = wm*64+mt*16+quad*4+r, n = wn8*64+nt*16+(lane&15)

    for (int ch = 0; ch < NCHUNK; ++ch) {
        const int gb = (ch << 6) + g4;
        const float4 kv = *(const float4*)&ke_s[gb];
        if (isB) {
            // ---- fx, channel-weighted -> B_lds[c*128 + x][g4..g4+3], x = grp*4+xi ----
            const float4 uv = *(const float4*)&u_s[gb];
            float e[4][4];
            #pragma unroll
            for (int xi = 0; xi < 4; ++xi) {
                const float xf = (float)(grp*4 + xi);
                float d;
                d = xf - uv.x; e[xi][0] = EXP2(kv.x*d*d);
                d = xf - uv.y; e[xi][1] = EXP2(kv.y*d*d);
                d = xf - uv.z; e[xi][2] = EXP2(kv.z*d*d);
                d = xf - uv.w; e[xi][3] = EXP2(kv.w*d*d);
            }
            #pragma unroll
            for (int c = 0; c < 4; ++c) {
                const float4 wv = *(const float4*)&wc_s[c][gb];
                #pragma unroll
                for (int xi = 0; xi < 4; ++xi) {
                    uint2 pk;
                    pk.x = bfpk2(e[xi][0]*wv.x, e[xi][1]*wv.y);
                    pk.y = bfpk2(e[xi][2]*wv.z, e[xi][3]*wv.w);
                    *(uint2*)&B_lds[(c << 7) + grp*4 + xi][g4] = pk;
                }
            }
        } else {
            // ---- fy -> A_lds[y][g4..g4+3], y = grp*4+yi ----
            const float4 vv = *(const float4*)&v_s[gb];
            #pragma unroll
            for (int yi = 0; yi < 4; ++yi) {
                const float yf = (float)(grp*4 + yi);
                float d, f0, f1, f2, f3;
                d = yf - vv.x; f0 = EXP2(kv.x*d*d);
                d = yf - vv.y; f1 = EXP2(kv.y*d*d);
                d = yf - vv.z; f2 = EXP2(kv.z*d*d);
                d = yf - vv.w; f3 = EXP2(kv.w*d*d);
                uint2 pk;
                pk.x = bfpk2(f0, f1); pk.y = bfpk2(f2, f3);
                *(uint2*)&A_lds[grp*4 + yi][g4] = pk;
            }
        }
        __syncthreads();
        // ---- MFMA: full K=64 chunk, 2 k-steps of 32 ----
        #pragma unroll
        for (int ks = 0; ks < 2; ++ks) {
            const int kcol = ks*32 + kqd;
            short8 a[4], b[4];
            #pragma unroll
            for (int mt = 0; mt < 4; ++mt)
                a[mt] = *(const short8*)&A_lds[wm*64 + mt*16 + frow][kcol];
            #pragma unroll
            for (int nt = 0; nt < 4; ++nt)
                b[nt] = *(const short8*)&B_lds[wn8*64 + nt*16 + frow][kcol];
            #pragma unroll
            for (int mt = 0; mt < 4; ++mt)
                #pragma unroll
                for (int nt = 0; nt < 4; ++nt)
                    acc[mt][nt] = __builtin_amdgcn_mfma_f32_16x16x32_bf16(a[mt], b[nt], acc[mt][nt], 0, 0, 0);
        }
        __syncthreads();
    }

    // ---- epilogue: every wave stores its [64m x 64n] tile ----
    const int q4 = (lane >> 4) << 2;          // 0,4,8,12
    const int n0 = wn8*64 + (lane & 15);
    if (STORE) {
        ushort* bp = pbuf + ((size_t)(pose*KSPLIT + split) * H_IMG + wm*64) * 512 + n0;
        #pragma unroll
        for (int mt = 0; mt < 4; ++mt)
            #pragma unroll
            for (int nt = 0; nt < 4; ++nt)
                #pragma unroll
                for (int r = 0; r < 4; ++r)
                    bp[(size_t)(mt*16 + q4 + r)*512 + nt*16] = bf16u(acc[mt][nt][r]);
    } else {
        float* bp = accum + ((size_t)(pose*H_IMG + wm*64) * 512) + n0;
        #pragma unroll
        for (int mt = 0; mt < 4; ++mt)
            #pragma unroll
            for (int nt = 0; nt < 4; ++nt)
                #pragma unroll
                for (int r = 0; r < 4; ++r)
                    atomicAdd(bp + (size_t)(mt*16 + q4 + r)*512 + nt*16, acc[mt][nt][r]);
    }
}

// STORE path: sum the 128 split partials (bf16), normalize, tiled output.
// grid 256 = (pose, y); 1024 threads = (s-half sg, n 0..511).
__global__ __launch_bounds__(1024) void reduce_norm_kernel(
    const ushort* __restrict__ pbuf, float* __restrict__ out)
{
    __shared__ float red[2][512];
    const int b  = blockIdx.x;
    const int p  = b >> 7;
    const int y  = b & 127;
    const int t  = threadIdx.x;
    const int sg = t >> 9;               // 0/1: splits [sg*64, sg*64+64)
    const int n  = t & 511;

    const ushort* base = pbuf + ((size_t)(p*KSPLIT + sg*64) * H_IMG + y) * 512 + n;
    float s = 0.0f;
    #pragma unroll 8
    for (int i = 0; i < 64; ++i) {
        unsigned us = base[(size_t)i * (H_IMG*512)];
        s += __uint_as_float(us << 16);
    }
    red[sg][n] = s;
    __syncthreads();

    if (t < 384) {
        const int c = t >> 7, x = t & 127;
        float den = red[0][384 + x] + red[1][384 + x];
        float num = red[0][t]       + red[1][t];
        float inv = 1.0f / (den + EPS_TOT);
        // output: [pose*16 + tile][3][32][32], tile = y>>3, q = (y&7)*128 + x
        int tt = y >> 3;
        int q  = ((y & 7) << 7) + x;
        out[(size_t)((p*16 + tt)*3 + c) * 1024 + q] = num * inv;
    }
}

// ATOMIC fallback: img = num/(den+eps), tiled output layout.
__global__ void normalize_kernel(const float* __restrict__ acc, float* __restrict__ out) {
    int idx = blockIdx.x * 256 + threadIdx.x;   // 0..32767 : (pose, y, x)
    int x = idx & 127;
    int y = (idx >> 7) & 127;
    int p = idx >> 14;
    const float* base = acc + (size_t)(p*128 + y) * 512;
    float inv = 1.0f / (base[384 + x] + EPS_TOT);
    int t = y >> 3;
    int q = ((y & 7) << 7) + x;
    float* ob = out + (size_t)((p*16 + t)*3) * 1024 + q;
    ob[0]    = base[x]       * inv;
    ob[1024] = base[128 + x] * inv;
    ob[2048] = base[256 + x] * inv;
}

extern "C" void kernel_launch(void* const* d_in, const int* in_sizes, int n_in,
                              void* d_out, int out_size, void* d_ws, size_t ws_size,
                              hipStream_t stream) {
    const float* gpos = (const float*)d_in[0];   // [65536,3]
    const float* gcol = (const float*)d_in[1];   // [65536,3]
    const float* gopa = (const float*)d_in[2];   // [65536,1]
    const float* gscl = (const float*)d_in[3];   // [65536,1]
    const float* qv   = (const float*)d_in[4];   // [2,4]
    const float* tv   = (const float*)d_in[5];   // [2,3]
    float* out = (float*)d_out;                  // [32,3,32,32] fp32

    // bf16 partials: 2 poses * 128 splits * 128 y * 512 n * 2B = 33,554,432 B
    const size_t need = (size_t)2 * KSPLIT * H_IMG * 512 * sizeof(ushort);

    if (ws_size >= need) {
        ushort* pbuf = (ushort*)d_ws;
        render_kernel<true><<<dim3(KSPLIT, 2), dim3(1024), 0, stream>>>(
            gpos, gcol, gopa, gscl, qv, tv, nullptr, pbuf);
        reduce_norm_kernel<<<dim3(256), dim3(1024), 0, stream>>>(pbuf, out);
    } else {
        float* acc = (float*)d_ws;               // 512 KB fp32 accumulator
        zero_accum_kernel<<<dim3(512), dim3(256), 0, stream>>>(acc);
        render_kernel<false><<<dim3(KSPLIT, 2), dim3(1024), 0, stream>>>(
            gpos, gcol, gopa, gscl, qv, tv, acc, nullptr);
        normalize_kernel<<<dim3(128), dim3(256), 0, stream>>>(acc, out);
    }
}

// Round 7
// 107.597 us; speedup vs baseline: 1.6992x; 1.0071x over previous
//
#include <hip/hip_runtime.h>

// Differentiable gaussian renderer, separable-splat formulation.
//
//   w(px,py) = op * exp(-0.5*((px-u)^2+(py-v)^2)/var)
//            = [exp2(ke*(py-v)^2)] * [exp2(ke*(px-u)^2)],  ke = -0.5*log2(e)/var
//
// => per pose: C[y][n] = sum_g A[y][g] * B[g][n],  n = c*128+x
//    A[y][g]       = fy_g(y),  B[g][c*128+x] = (op*color_c)_g * fx_g(x)
//    (c=3: color=1 -> denominator)
//
// R6 -> R7: R6's 2-barriers-per-chunk serialized staging (exp+LDS-write)
// against MFMA (ds_read+matrix pipe); with 1 block/CU nothing fills the
// bubbles. Now: K=32 chunks, DOUBLE-BUFFERED LDS tiles, ONE barrier per
// chunk -> stage(ch+1) overlaps MFMA(ch) across the 16 waves. Total LDS
// bytes / exps / MFMA count / accumulation order identical to R6 (absmax
// anchor 0.0078125). Reduce kernel: uint4 loads (8 bf16), 8-deep ILP.

#define H_IMG 128
#define W_IMG 128
#define FX_C 120.0f
#define FY_C 120.0f
#define CX_C 64.0f
#define CY_C 64.0f
#define NG 65536
#define SLAB 512          // gaussians per block
#define KSPLIT 128        // NG / SLAB
#define KC 32             // gaussians per LDS chunk
#define NCH 16            // SLAB / KC
#define KPAD 40           // 32 + 8 bf16 pad: row stride 80B (16B aligned)
#define NEG_HALF_LOG2E -0.72134752044448170f
#define EPS_TOT 1.6e-7f   // n_chunks(16) * 1e-8

#if __has_builtin(__builtin_amdgcn_exp2f)
#define EXP2(x) __builtin_amdgcn_exp2f(x)
#else
#define EXP2(x) exp2f(x)
#endif

typedef __attribute__((ext_vector_type(8))) short short8;   // 8 bf16 = 4 VGPRs
typedef __attribute__((ext_vector_type(4))) float f32x4;    // MFMA acc

// pack two f32 -> two bf16 (round-half-up) in 3 VALU ops via v_perm_b32.
__device__ __forceinline__ unsigned bfpk2(float a, float b) {
    return __builtin_amdgcn_perm(__float_as_uint(b) + 0x8000u,
                                 __float_as_uint(a) + 0x8000u,
                                 0x07060302u);
}
__device__ __forceinline__ ushort bf16u(float v) {
    return (ushort)((__float_as_uint(v) + 0x8000u) >> 16);
}

__global__ void zero_accum_kernel(float* __restrict__ p) {
    p[blockIdx.x * 256 + threadIdx.x] = 0.0f;   // grid 512 x 256 = 131072 floats
}

// grid dim3(128, 2): blockIdx.x = K-split, blockIdx.y = pose
template <bool STORE>
__global__ __launch_bounds__(1024, 4) void render_kernel(
    const float* __restrict__ gpos, const float* __restrict__ gcol,
    const float* __restrict__ gopa, const float* __restrict__ gscl,
    const float* __restrict__ qvec, const float* __restrict__ tvec,
    float* __restrict__ accum,                 // ATOMIC path: [2][128 y][512 n] fp32
    ushort* __restrict__ pbuf)                 // STORE path: [2][128 s][128 y][512 n] bf16
{
    __shared__ ushort A_lds[2][H_IMG][KPAD];         // fy,  [buf][y][k]   20 KB
    __shared__ ushort B_lds[2][512][KPAD];           // B^T, [buf][n][k]   80 KB
    __shared__ float u_s[SLAB], v_s[SLAB], ke_s[SLAB];
    __shared__ float wc_s[4][SLAB];                  // op*{r,g,b,1}

    const int split = blockIdx.x;                    // 0..127
    const int pose  = blockIdx.y;                    // 0..1
    const int tid   = threadIdx.x;                   // 0..1023

    // ---- camera: quaternion -> R ----
    float q0 = qvec[pose*4+0], q1 = qvec[pose*4+1], q2 = qvec[pose*4+2], q3 = qvec[pose*4+3];
    float rn = rsqrtf(q0*q0 + q1*q1 + q2*q2 + q3*q3);
    float qw = q0*rn, qx = q1*rn, qy = q2*rn, qz = q3*rn;
    float r00 = 1.0f-2.0f*(qy*qy+qz*qz), r01 = 2.0f*(qx*qy-qz*qw), r02 = 2.0f*(qx*qz+qy*qw);
    float r10 = 2.0f*(qx*qy+qz*qw), r11 = 1.0f-2.0f*(qx*qx+qz*qz), r12 = 2.0f*(qy*qz-qx*qw);
    float r20 = 2.0f*(qx*qz-qy*qw), r21 = 2.0f*(qy*qz+qx*qw), r22 = 1.0f-2.0f*(qx*qx+qy*qy);
    float tx = tvec[pose*3+0], ty = tvec[pose*3+1], tz = tvec[pose*3+2];

    // ---- per-slab gaussian params, staged once (512 g, 1/thread) ----
    if (tid < SLAB) {
        int g = split*SLAB + tid;
        float p0 = gpos[g*3+0], p1 = gpos[g*3+1], p2 = gpos[g*3+2];
        float cxm = r00*p0 + r01*p1 + r02*p2 + tx;
        float cym = r10*p0 + r11*p1 + r12*p2 + ty;
        float czm = r20*p0 + r21*p1 + r22*p2 + tz;
        float iz  = 1.0f / czm;
        u_s[tid] = cxm*iz*FX_C + CX_C;
        v_s[tid] = cym*iz*FY_C + CY_C;
        float s  = gscl[g];
        ke_s[tid] = NEG_HALF_LOG2E / (s*s);
        float og = gopa[g];
        wc_s[0][tid] = og * gcol[g*3+0];
        wc_s[1][tid] = og * gcol[g*3+1];
        wc_s[2][tid] = og * gcol[g*3+2];
        wc_s[3][tid] = og;
    }
    __syncthreads();

    const int lane = tid & 63;
    const int wave = tid >> 6;            // 0..15
    const int wm   = wave >> 3;           // m band: [wm*64, wm*64+64)
    const int wn8  = wave & 7;            // n band: [wn8*64, wn8*64+64)

    // staging roles per K=32 chunk:
    //   threads 0..511   stage B: 4g x 2x x 4c  (8 exps)
    //   threads 512..1023 stage A: 4g x 2y      (8 exps)
    const bool isB = (tid < 512);
    const int st   = tid & 511;
    const int g4   = (st & 7) << 2;       // 0,4,..,28
    const int rg   = st >> 3;             // 0..63 -> rows rg*2, rg*2+1

    // MFMA frag addressing (verified 16x16x32 bf16 layouts)
    const int frow = lane & 15;
    const int kq   = (lane >> 4) << 3;    // k = quad*8 + j

    f32x4 acc[4][4] = {};  // [mt][nt]: m = wm*64+mt*16+quad*4+r, n = wn8*64+nt*16+(lane&15)

    // ---- staging lambda-equivalent macro body, chunk ch -> buffer b ----
#define STAGE_CHUNK(ch, b)                                                     \
    {                                                                          \
        const int gb = ((ch) << 5) + g4;                                       \
        const float4 kv = *(const float4*)&ke_s[gb];                           \
        if (isB) {                                                             \
            const float4 uv = *(const float4*)&u_s[gb];                        \
            float e[2][4];                                                     \
            _Pragma("unroll")                                                  \
            for (int xi = 0; xi < 2; ++xi) {                                   \
                const float xf = (float)(rg*2 + xi);                           \
                float d;                                                       \
                d = xf - uv.x; e[xi][0] = EXP2(kv.x*d*d);                      \
                d = xf - uv.y; e[xi][1] = EXP2(kv.y*d*d);                      \
                d = xf - uv.z; e[xi][2] = EXP2(kv.z*d*d);                      \
                d = xf - uv.w; e[xi][3] = EXP2(kv.w*d*d);                      \
            }                                                                  \
            _Pragma("unroll")                                                  \
            for (int c = 0; c < 4; ++c) {                                      \
                const float4 wv = *(const float4*)&wc_s[c][gb];                \
                _Pragma("unroll")                                              \
                for (int xi = 0; xi < 2; ++xi) {                               \
                    uint2 pk;                                                  \
                    pk.x = bfpk2(e[xi][0]*wv.x, e[xi][1]*wv.y);                \
                    pk.y = bfpk2(e[xi][2]*wv.z, e[xi][3]*wv.w);                \
                    *(uint2*)&B_lds[b][(c << 7) + rg*2 + xi][g4] = pk;         \
                }                                                              \
            }                                                                  \
        } else {                                                               \
            const float4 vv = *(const float4*)&v_s[gb];                        \
            _Pragma("unroll")                                                  \
            for (int yi = 0; yi < 2; ++yi) {                                   \
                const float yf = (float)(rg*2 + yi);                           \
                float d, f0, f1, f2, f3;                                       \
                d = yf - vv.x; f0 = EXP2(kv.x*d*d);                            \
                d = yf - vv.y; f1 = EXP2(kv.y*d*d);                            \
                d = yf - vv.z; f2 = EXP2(kv.z*d*d);                            \
                d = yf - vv.w; f3 = EXP2(kv.w*d*d);                            \
                uint2 pk;                                                      \
                pk.x = bfpk2(f0, f1); pk.y = bfpk2(f2, f3);                    \
                *(uint2*)&A_lds[b][rg*2 + yi][g4] = pk;                        \
            }                                                                  \
        }                                                                      \
    }

    // prologue: stage chunk 0 into buffer 0
    STAGE_CHUNK(0, 0)

    for (int ch = 0; ch < NCH; ++ch) {
        __syncthreads();   // chunk ch fully staged; own reads of buf (ch+1)&1 drained
        // stage next chunk into the other buffer (overlaps with MFMA below)
        if (ch + 1 < NCH) {
            const int nb = (ch + 1) & 1;
            STAGE_CHUNK(ch + 1, nb)
        }
        // MFMA on chunk ch from buffer ch&1 (K=32, one step)
        {
            const int cb = ch & 1;
            short8 a[4], b[4];
            #pragma unroll
            for (int mt = 0; mt < 4; ++mt)
                a[mt] = *(const short8*)&A_lds[cb][wm*64 + mt*16 + frow][kq];
            #pragma unroll
            for (int nt = 0; nt < 4; ++nt)
                b[nt] = *(const short8*)&B_lds[cb][wn8*64 + nt*16 + frow][kq];
            #pragma unroll
            for (int mt = 0; mt < 4; ++mt)
                #pragma unroll
                for (int nt = 0; nt < 4; ++nt)
                    acc[mt][nt] = __builtin_amdgcn_mfma_f32_16x16x32_bf16(a[mt], b[nt], acc[mt][nt], 0, 0, 0);
        }
    }
#undef STAGE_CHUNK

    // ---- epilogue: every wave stores its [64m x 64n] tile ----
    const int q4 = (lane >> 4) << 2;          // 0,4,8,12
    const int n0 = wn8*64 + (lane & 15);
    if (STORE) {
        ushort* bp = pbuf + ((size_t)(pose*KSPLIT + split) * H_IMG + wm*64) * 512 + n0;
        #pragma unroll
        for (int mt = 0; mt < 4; ++mt)
            #pragma unroll
            for (int nt = 0; nt < 4; ++nt)
                #pragma unroll
                for (int r = 0; r < 4; ++r)
                    bp[(size_t)(mt*16 + q4 + r)*512 + nt*16] = bf16u(acc[mt][nt][r]);
    } else {
        float* bp = accum + ((size_t)(pose*H_IMG + wm*64) * 512) + n0;
        #pragma unroll
        for (int mt = 0; mt < 4; ++mt)
            #pragma unroll
            for (int nt = 0; nt < 4; ++nt)
                #pragma unroll
                for (int r = 0; r < 4; ++r)
                    atomicAdd(bp + (size_t)(mt*16 + q4 + r)*512 + nt*16, acc[mt][nt][r]);
    }
}

// STORE path: sum the 128 bf16 split partials, normalize, tiled output.
// grid 256 = (pose, y); 1024 threads = (split-group sg 0..15, n-octet ng 0..63).
__global__ __launch_bounds__(1024) void reduce_norm_kernel(
    const ushort* __restrict__ pbuf, float* __restrict__ out)
{
    __shared__ float red[16][512];       // 32 KB
    __shared__ float tot[512];
    const int b  = blockIdx.x;
    const int p  = b >> 7;
    const int y  = b & 127;
    const int t  = threadIdx.x;
    const int sg = t >> 6;               // 0..15: splits [sg*8, sg*8+8)
    const int ng = t & 63;               // n octet: n = ng*8 .. ng*8+7

    const uint4* base = (const uint4*)(pbuf +
        ((size_t)(p*KSPLIT + sg*8) * H_IMG + y) * 512 + ng*8);
    float s[8] = {};
    #pragma unroll
    for (int i = 0; i < 8; ++i) {
        uint4 v = base[(size_t)i * (H_IMG*512/8)];
        s[0] += __uint_as_float(v.x << 16);
        s[1] += __uint_as_float(v.x & 0xFFFF0000u);
        s[2] += __uint_as_float(v.y << 16);
        s[3] += __uint_as_float(v.y & 0xFFFF0000u);
        s[4] += __uint_as_float(v.z << 16);
        s[5] += __uint_as_float(v.z & 0xFFFF0000u);
        s[6] += __uint_as_float(v.w << 16);
        s[7] += __uint_as_float(v.w & 0xFFFF0000u);
    }
    #pragma unroll
    for (int j = 0; j < 8; ++j) red[sg][ng*8 + j] = s[j];
    __syncthreads();

    if (t < 512) {
        float acc = 0.0f;
        #pragma unroll
        for (int g = 0; g < 16; ++g) acc += red[g][t];
        tot[t] = acc;
    }
    __syncthreads();

    if (t < 384) {
        const int c = t >> 7, x = t & 127;
        float inv = 1.0f / (tot[384 + x] + EPS_TOT);
        // output: [pose*16 + tile][3][32][32], tile = y>>3, q = (y&7)*128 + x
        int tt = y >> 3;
        int q  = ((y & 7) << 7) + x;
        out[(size_t)((p*16 + tt)*3 + c) * 1024 + q] = tot[t] * inv;
    }
}

// ATOMIC fallback: img = num/(den+eps), tiled output layout.
__global__ void normalize_kernel(const float* __restrict__ acc, float* __restrict__ out) {
    int idx = blockIdx.x * 256 + threadIdx.x;   // 0..32767 : (pose, y, x)
    int x = idx & 127;
    int y = (idx >> 7) & 127;
    int p = idx >> 14;
    const float* base = acc + (size_t)(p*128 + y) * 512;
    float inv = 1.0f / (base[384 + x] + EPS_TOT);
    int t = y >> 3;
    int q = ((y & 7) << 7) + x;
    float* ob = out + (size_t)((p*16 + t)*3) * 1024 + q;
    ob[0]    = base[x]       * inv;
    ob[1024] = base[128 + x] * inv;
    ob[2048] = base[256 + x] * inv;
}

extern "C" void kernel_launch(void* const* d_in, const int* in_sizes, int n_in,
                              void* d_out, int out_size, void* d_ws, size_t ws_size,
                              hipStream_t stream) {
    const float* gpos = (const float*)d_in[0];   // [65536,3]
    const float* gcol = (const float*)d_in[1];   // [65536,3]
    const float* gopa = (const float*)d_in[2];   // [65536,1]
    const float* gscl = (const float*)d_in[3];   // [65536,1]
    const float* qv   = (const float*)d_in[4];   // [2,4]
    const float* tv   = (const float*)d_in[5];   // [2,3]
    float* out = (float*)d_out;                  // [32,3,32,32] fp32

    // bf16 partials: 2 poses * 128 splits * 128 y * 512 n * 2B = 33,554,432 B
    const size_t need = (size_t)2 * KSPLIT * H_IMG * 512 * sizeof(ushort);

    if (ws_size >= need) {
        ushort* pbuf = (ushort*)d_ws;
        render_kernel<true><<<dim3(KSPLIT, 2), dim3(1024), 0, stream>>>(
            gpos, gcol, gopa, gscl, qv, tv, nullptr, pbuf);
        reduce_norm_kernel<<<dim3(256), dim3(1024), 0, stream>>>(pbuf, out);
    } else {
        float* acc = (float*)d_ws;               // 512 KB fp32 accumulator
        zero_accum_kernel<<<dim3(512), dim3(256), 0, stream>>>(acc);
        render_kernel<false><<<dim3(KSPLIT, 2), dim3(1024), 0, stream>>>(
            gpos, gcol, gopa, gscl, qv, tv, acc, nullptr);
        normalize_kernel<<<dim3(128), dim3(256), 0, stream>>>(acc, out);
    }
}

// Round 10
// 107.352 us; speedup vs baseline: 1.7031x; 1.0023x over previous
//
#include <hip/hip_runtime.h>

// Differentiable gaussian renderer, separable-splat formulation.
//
//   w(px,py) = op * exp(-0.5*((px-u)^2+(py-v)^2)/var)
//            = [exp2(ke*(py-v)^2)] * [exp2(ke*(px-u)^2)],  ke = -0.5*log2(e)/var
//
// => per pose: C[y][n] = sum_g A[y][g] * B[g][n],  n = c*128+x
//    A[y][g]       = fy_g(y),  B[g][c*128+x] = (op*color_c)_g * fx_g(x)
//    (c=3: color=1 -> denominator)
//
// R9 -> R10: R8/R9 (512-thread render, grid (128,4), 2 blocks/CU) both
// passed eager validation (absmax 0.0078125) but failed the post-replay
// re-check - a timing-sensitive signature confined to that compiled
// configuration. All passing rounds used 1024-thread renders on 256-block
// grids. Reverting to the R7 source verbatim (last passing kernel):
// K=32 double-buffered chunks, one barrier per chunk, bf16 partials,
// uint4-vectorized reduce.

#define H_IMG 128
#define W_IMG 128
#define FX_C 120.0f
#define FY_C 120.0f
#define CX_C 64.0f
#define CY_C 64.0f
#define NG 65536
#define SLAB 512          // gaussians per block
#define KSPLIT 128        // NG / SLAB
#define KC 32             // gaussians per LDS chunk
#define NCH 16            // SLAB / KC
#define KPAD 40           // 32 + 8 bf16 pad: row stride 80B (16B aligned)
#define NEG_HALF_LOG2E -0.72134752044448170f
#define EPS_TOT 1.6e-7f   // n_chunks(16) * 1e-8

#if __has_builtin(__builtin_amdgcn_exp2f)
#define EXP2(x) __builtin_amdgcn_exp2f(x)
#else
#define EXP2(x) exp2f(x)
#endif

typedef __attribute__((ext_vector_type(8))) short short8;   // 8 bf16 = 4 VGPRs
typedef __attribute__((ext_vector_type(4))) float f32x4;    // MFMA acc

// pack two f32 -> two bf16 (round-half-up) in 3 VALU ops via v_perm_b32.
__device__ __forceinline__ unsigned bfpk2(float a, float b) {
    return __builtin_amdgcn_perm(__float_as_uint(b) + 0x8000u,
                                 __float_as_uint(a) + 0x8000u,
                                 0x07060302u);
}
__device__ __forceinline__ ushort bf16u(float v) {
    return (ushort)((__float_as_uint(v) + 0x8000u) >> 16);
}

__global__ void zero_accum_kernel(float* __restrict__ p) {
    p[blockIdx.x * 256 + threadIdx.x] = 0.0f;   // grid 512 x 256 = 131072 floats
}

// grid dim3(128, 2): blockIdx.x = K-split, blockIdx.y = pose
template <bool STORE>
__global__ __launch_bounds__(1024, 4) void render_kernel(
    const float* __restrict__ gpos, const float* __restrict__ gcol,
    const float* __restrict__ gopa, const float* __restrict__ gscl,
    const float* __restrict__ qvec, const float* __restrict__ tvec,
    float* __restrict__ accum,                 // ATOMIC path: [2][128 y][512 n] fp32
    ushort* __restrict__ pbuf)                 // STORE path: [2][128 s][128 y][512 n] bf16
{
    __shared__ ushort A_lds[2][H_IMG][KPAD];         // fy,  [buf][y][k]   20 KB
    __shared__ ushort B_lds[2][512][KPAD];           // B^T, [buf][n][k]   80 KB
    __shared__ float u_s[SLAB], v_s[SLAB], ke_s[SLAB];
    __shared__ float wc_s[4][SLAB];                  // op*{r,g,b,1}

    const int split = blockIdx.x;                    // 0..127
    const int pose  = blockIdx.y;                    // 0..1
    const int tid   = threadIdx.x;                   // 0..1023

    // ---- camera: quaternion -> R ----
    float q0 = qvec[pose*4+0], q1 = qvec[pose*4+1], q2 = qvec[pose*4+2], q3 = qvec[pose*4+3];
    float rn = rsqrtf(q0*q0 + q1*q1 + q2*q2 + q3*q3);
    float qw = q0*rn, qx = q1*rn, qy = q2*rn, qz = q3*rn;
    float r00 = 1.0f-2.0f*(qy*qy+qz*qz), r01 = 2.0f*(qx*qy-qz*qw), r02 = 2.0f*(qx*qz+qy*qw);
    float r10 = 2.0f*(qx*qy+qz*qw), r11 = 1.0f-2.0f*(qx*qx+qz*qz), r12 = 2.0f*(qy*qz-qx*qw);
    float r20 = 2.0f*(qx*qz-qy*qw), r21 = 2.0f*(qy*qz+qx*qw), r22 = 1.0f-2.0f*(qx*qx+qy*qy);
    float tx = tvec[pose*3+0], ty = tvec[pose*3+1], tz = tvec[pose*3+2];

    // ---- per-slab gaussian params, staged once (512 g, 1/thread) ----
    if (tid < SLAB) {
        int g = split*SLAB + tid;
        float p0 = gpos[g*3+0], p1 = gpos[g*3+1], p2 = gpos[g*3+2];
        float cxm = r00*p0 + r01*p1 + r02*p2 + tx;
        float cym = r10*p0 + r11*p1 + r12*p2 + ty;
        float czm = r20*p0 + r21*p1 + r22*p2 + tz;
        float iz  = 1.0f / czm;
        u_s[tid] = cxm*iz*FX_C + CX_C;
        v_s[tid] = cym*iz*FY_C + CY_C;
        float s  = gscl[g];
        ke_s[tid] = NEG_HALF_LOG2E / (s*s);
        float og = gopa[g];
        wc_s[0][tid] = og * gcol[g*3+0];
        wc_s[1][tid] = og * gcol[g*3+1];
        wc_s[2][tid] = og * gcol[g*3+2];
        wc_s[3][tid] = og;
    }
    __syncthreads();

    const int lane = tid & 63;
    const int wave = tid >> 6;            // 0..15
    const int wm   = wave >> 3;           // m band: [wm*64, wm*64+64)
    const int wn8  = wave & 7;            // n band: [wn8*64, wn8*64+64)

    // staging roles per K=32 chunk:
    //   threads 0..511   stage B: 4g x 2x x 4c  (8 exps)
    //   threads 512..1023 stage A: 4g x 2y      (8 exps)
    const bool isB = (tid < 512);
    const int st   = tid & 511;
    const int g4   = (st & 7) << 2;       // 0,4,..,28
    const int rg   = st >> 3;             // 0..63 -> rows rg*2, rg*2+1

    // MFMA frag addressing (verified 16x16x32 bf16 layouts)
    const int frow = lane & 15;
    const int kq   = (lane >> 4) << 3;    // k = quad*8 + j

    f32x4 acc[4][4] = {};  // [mt][nt]: m = wm*64+mt*16+quad*4+r, n = wn8*64+nt*16+(lane&15)

    // ---- staging macro body, chunk ch -> buffer b ----
#define STAGE_CHUNK(ch, b)                                                     \
    {                                                                          \
        const int gb = ((ch) << 5) + g4;                                       \
        const float4 kv = *(const float4*)&ke_s[gb];                           \
        if (isB) {                                                             \
            const float4 uv = *(const float4*)&u_s[gb];                        \
            float e[2][4];                                                     \
            _Pragma("unroll")                                                  \
            for (int xi = 0; xi < 2; ++xi) {                                   \
                const float xf = (float)(rg*2 + xi);                           \
                float d;                                                       \
                d = xf - uv.x; e[xi][0] = EXP2(kv.x*d*d);                      \
                d = xf - uv.y; e[xi][1] = EXP2(kv.y*d*d);                      \
                d = xf - uv.z; e[xi][2] = EXP2(kv.z*d*d);                      \
                d = xf - uv.w; e[xi][3] = EXP2(kv.w*d*d);                      \
            }                                                                  \
            _Pragma("unroll")                                                  \
            for (int c = 0; c < 4; ++c) {                                      \
                const float4 wv = *(const float4*)&wc_s[c][gb];                \
                _Pragma("unroll")                                              \
                for (int xi = 0; xi < 2; ++xi) {                               \
                    uint2 pk;                                                  \
                    pk.x = bfpk2(e[xi][0]*wv.x, e[xi][1]*wv.y);                \
                    pk.y = bfpk2(e[xi][2]*wv.z, e[xi][3]*wv.w);                \
                    *(uint2*)&B_lds[b][(c << 7) + rg*2 + xi][g4] = pk;         \
                }                                                              \
            }                                                                  \
        } else {                                                               \
            const float4 vv = *(const float4*)&v_s[gb];                        \
            _Pragma("unroll")                                                  \
            for (int yi = 0; yi < 2; ++yi) {                                   \
                const float yf = (float)(rg*2 + yi);                           \
                float d, f0, f1, f2, f3;                                       \
                d = yf - vv.x; f0 = EXP2(kv.x*d*d);                            \
                d = yf - vv.y; f1 = EXP2(kv.y*d*d);                            \
                d = yf - vv.z; f2 = EXP2(kv.z*d*d);                            \
                d = yf - vv.w; f3 = EXP2(kv.w*d*d);                            \
                uint2 pk;                                                      \
                pk.x = bfpk2(f0, f1); pk.y = bfpk2(f2, f3);                    \
                *(uint2*)&A_lds[b][rg*2 + yi][g4] = pk;                        \
            }                                                                  \
        }                                                                      \
    }

    // prologue: stage chunk 0 into buffer 0
    STAGE_CHUNK(0, 0)

    for (int ch = 0; ch < NCH; ++ch) {
        __syncthreads();   // chunk ch fully staged; own reads of buf (ch+1)&1 drained
        // stage next chunk into the other buffer (overlaps with MFMA below)
        if (ch + 1 < NCH) {
            const int nb = (ch + 1) & 1;
            STAGE_CHUNK(ch + 1, nb)
        }
        // MFMA on chunk ch from buffer ch&1 (K=32, one step)
        {
            const int cb = ch & 1;
            short8 a[4], b[4];
            #pragma unroll
            for (int mt = 0; mt < 4; ++mt)
                a[mt] = *(const short8*)&A_lds[cb][wm*64 + mt*16 + frow][kq];
            #pragma unroll
            for (int nt = 0; nt < 4; ++nt)
                b[nt] = *(const short8*)&B_lds[cb][wn8*64 + nt*16 + frow][kq];
            #pragma unroll
            for (int mt = 0; mt < 4; ++mt)
                #pragma unroll
                for (int nt = 0; nt < 4; ++nt)
                    acc[mt][nt] = __builtin_amdgcn_mfma_f32_16x16x32_bf16(a[mt], b[nt], acc[mt][nt], 0, 0, 0);
        }
    }
#undef STAGE_CHUNK

    // ---- epilogue: every wave stores its [64m x 64n] tile ----
    const int q4 = (lane >> 4) << 2;          // 0,4,8,12
    const int n0 = wn8*64 + (lane & 15);
    if (STORE) {
        ushort* bp = pbuf + ((size_t)(pose*KSPLIT + split) * H_IMG + wm*64) * 512 + n0;
        #pragma unroll
        for (int mt = 0; mt < 4; ++mt)
            #pragma unroll
            for (int nt = 0; nt < 4; ++nt)
                #pragma unroll
                for (int r = 0; r < 4; ++r)
                    bp[(size_t)(mt*16 + q4 + r)*512 + nt*16] = bf16u(acc[mt][nt][r]);
    } else {
        float* bp = accum + ((size_t)(pose*H_IMG + wm*64) * 512) + n0;
        #pragma unroll
        for (int mt = 0; mt < 4; ++mt)
            #pragma unroll
            for (int nt = 0; nt < 4; ++nt)
                #pragma unroll
                for (int r = 0; r < 4; ++r)
                    atomicAdd(bp + (size_t)(mt*16 + q4 + r)*512 + nt*16, acc[mt][nt][r]);
    }
}

// STORE path: sum the 128 bf16 split partials, normalize, tiled output.
// grid 256 = (pose, y); 1024 threads = (split-group sg 0..15, n-octet ng 0..63).
__global__ __launch_bounds__(1024) void reduce_norm_kernel(
    const ushort* __restrict__ pbuf, float* __restrict__ out)
{
    __shared__ float red[16][512];       // 32 KB
    __shared__ float tot[512];
    const int b  = blockIdx.x;
    const int p  = b >> 7;
    const int y  = b & 127;
    const int t  = threadIdx.x;
    const int sg = t >> 6;               // 0..15: splits [sg*8, sg*8+8)
    const int ng = t & 63;               // n octet: n = ng*8 .. ng*8+7

    const uint4* base = (const uint4*)(pbuf +
        ((size_t)(p*KSPLIT + sg*8) * H_IMG + y) * 512 + ng*8);
    float s[8] = {};
    #pragma unroll
    for (int i = 0; i < 8; ++i) {
        uint4 v = base[(size_t)i * (H_IMG*512/8)];
        s[0] += __uint_as_float(v.x << 16);
        s[1] += __uint_as_float(v.x & 0xFFFF0000u);
        s[2] += __uint_as_float(v.y << 16);
        s[3] += __uint_as_float(v.y & 0xFFFF0000u);
        s[4] += __uint_as_float(v.z << 16);
        s[5] += __uint_as_float(v.z & 0xFFFF0000u);
        s[6] += __uint_as_float(v.w << 16);
        s[7] += __uint_as_float(v.w & 0xFFFF0000u);
    }
    #pragma unroll
    for (int j = 0; j < 8; ++j) red[sg][ng*8 + j] = s[j];
    __syncthreads();

    if (t < 512) {
        float acc = 0.0f;
        #pragma unroll
        for (int g = 0; g < 16; ++g) acc += red[g][t];
        tot[t] = acc;
    }
    __syncthreads();

    if (t < 384) {
        const int c = t >> 7, x = t & 127;
        float inv = 1.0f / (tot[384 + x] + EPS_TOT);
        // output: [pose*16 + tile][3][32][32], tile = y>>3, q = (y&7)*128 + x
        int tt = y >> 3;
        int q  = ((y & 7) << 7) + x;
        out[(size_t)((p*16 + tt)*3 + c) * 1024 + q] = tot[t] * inv;
    }
}

// ATOMIC fallback: img = num/(den+eps), tiled output layout.
__global__ void normalize_kernel(const float* __restrict__ acc, float* __restrict__ out) {
    int idx = blockIdx.x * 256 + threadIdx.x;   // 0..32767 : (pose, y, x)
    int x = idx & 127;
    int y = (idx >> 7) & 127;
    int p = idx >> 14;
    const float* base = acc + (size_t)(p*128 + y) * 512;
    float inv = 1.0f / (base[384 + x] + EPS_TOT);
    int t = y >> 3;
    int q = ((y & 7) << 7) + x;
    float* ob = out + (size_t)((p*16 + t)*3) * 1024 + q;
    ob[0]    = base[x]       * inv;
    ob[1024] = base[128 + x] * inv;
    ob[2048] = base[256 + x] * inv;
}

extern "C" void kernel_launch(void* const* d_in, const int* in_sizes, int n_in,
                              void* d_out, int out_size, void* d_ws, size_t ws_size,
                              hipStream_t stream) {
    const float* gpos = (const float*)d_in[0];   // [65536,3]
    const float* gcol = (const float*)d_in[1];   // [65536,3]
    const float* gopa = (const float*)d_in[2];   // [65536,1]
    const float* gscl = (const float*)d_in[3];   // [65536,1]
    const float* qv   = (const float*)d_in[4];   // [2,4]
    const float* tv   = (const float*)d_in[5];   // [2,3]
    float* out = (float*)d_out;                  // [32,3,32,32] fp32

    // bf16 partials: 2 poses * 128 splits * 128 y * 512 n * 2B = 33,554,432 B
    const size_t need = (size_t)2 * KSPLIT * H_IMG * 512 * sizeof(ushort);

    if (ws_size >= need) {
        ushort* pbuf = (ushort*)d_ws;
        render_kernel<true><<<dim3(KSPLIT, 2), dim3(1024), 0, stream>>>(
            gpos, gcol, gopa, gscl, qv, tv, nullptr, pbuf);
        reduce_norm_kernel<<<dim3(256), dim3(1024), 0, stream>>>(pbuf, out);
    } else {
        float* acc = (float*)d_ws;               // 512 KB fp32 accumulator
        zero_accum_kernel<<<dim3(512), dim3(256), 0, stream>>>(acc);
        render_kernel<false><<<dim3(KSPLIT, 2), dim3(1024), 0, stream>>>(
            gpos, gcol, gopa, gscl, qv, tv, acc, nullptr);
        normalize_kernel<<<dim3(128), dim3(256), 0, stream>>>(acc, out);
    }
}

// Round 11
// 106.908 us; speedup vs baseline: 1.7102x; 1.0042x over previous
//
#include <hip/hip_runtime.h>

// Differentiable gaussian renderer, separable-splat formulation.
//
//   w(px,py) = op * exp(-0.5*((px-u)^2+(py-v)^2)/var)
//            = [exp2(ke*(py-v)^2)] * [exp2(ke*(px-u)^2)],  ke = -0.5*log2(e)/var
//
// => per pose: C[y][n] = sum_g A[y][g] * B[g][n],  n = c*128+x
//    A[y][g]       = fy_g(y),  B[g][c*128+x] = (op*color_c)_g * fx_g(x)
//    (c=3: color=1 -> denominator)
//
// R10 -> R11: R7's dbuf was neutral because all 16 waves leave each barrier
// in lockstep and run stage-then-MFMA in the same program order -> VALU
// phase and LDS/MFMA phase still serialize chip-wide. Fix (within the
// replay-proven 1024-thr/(128,2) config): STAGGER the per-wave order -
// B-staging waves (0-7) stage(ch+1) then MFMA(ch); A-staging waves (8-15)
// MFMA(ch) then stage(ch+1). Each SIMD gets 2 waves of each order -> exp
// VALU overlaps ds_read/MFMA structurally. Per-wave MFMA order unchanged
// (absmax anchor 0.0078125). 2-blocks/CU direction abandoned (2x replay
// validation failures).

#define H_IMG 128
#define W_IMG 128
#define FX_C 120.0f
#define FY_C 120.0f
#define CX_C 64.0f
#define CY_C 64.0f
#define NG 65536
#define SLAB 512          // gaussians per block
#define KSPLIT 128        // NG / SLAB
#define KC 32             // gaussians per LDS chunk
#define NCH 16            // SLAB / KC
#define KPAD 40           // 32 + 8 bf16 pad: row stride 80B (16B aligned)
#define NEG_HALF_LOG2E -0.72134752044448170f
#define EPS_TOT 1.6e-7f   // n_chunks(16) * 1e-8

#if __has_builtin(__builtin_amdgcn_exp2f)
#define EXP2(x) __builtin_amdgcn_exp2f(x)
#else
#define EXP2(x) exp2f(x)
#endif

typedef __attribute__((ext_vector_type(8))) short short8;   // 8 bf16 = 4 VGPRs
typedef __attribute__((ext_vector_type(4))) float f32x4;    // MFMA acc

// pack two f32 -> two bf16 (round-half-up) in 3 VALU ops via v_perm_b32.
__device__ __forceinline__ unsigned bfpk2(float a, float b) {
    return __builtin_amdgcn_perm(__float_as_uint(b) + 0x8000u,
                                 __float_as_uint(a) + 0x8000u,
                                 0x07060302u);
}
__device__ __forceinline__ ushort bf16u(float v) {
    return (ushort)((__float_as_uint(v) + 0x8000u) >> 16);
}

__global__ void zero_accum_kernel(float* __restrict__ p) {
    p[blockIdx.x * 256 + threadIdx.x] = 0.0f;   // grid 512 x 256 = 131072 floats
}

// grid dim3(128, 2): blockIdx.x = K-split, blockIdx.y = pose
template <bool STORE>
__global__ __launch_bounds__(1024, 4) void render_kernel(
    const float* __restrict__ gpos, const float* __restrict__ gcol,
    const float* __restrict__ gopa, const float* __restrict__ gscl,
    const float* __restrict__ qvec, const float* __restrict__ tvec,
    float* __restrict__ accum,                 // ATOMIC path: [2][128 y][512 n] fp32
    ushort* __restrict__ pbuf)                 // STORE path: [2][128 s][128 y][512 n] bf16
{
    __shared__ ushort A_lds[2][H_IMG][KPAD];         // fy,  [buf][y][k]   20 KB
    __shared__ ushort B_lds[2][512][KPAD];           // B^T, [buf][n][k]   80 KB
    __shared__ float u_s[SLAB], v_s[SLAB], ke_s[SLAB];
    __shared__ float wc_s[4][SLAB];                  // op*{r,g,b,1}

    const int split = blockIdx.x;                    // 0..127
    const int pose  = blockIdx.y;                    // 0..1
    const int tid   = threadIdx.x;                   // 0..1023

    // ---- camera: quaternion -> R ----
    float q0 = qvec[pose*4+0], q1 = qvec[pose*4+1], q2 = qvec[pose*4+2], q3 = qvec[pose*4+3];
    float rn = rsqrtf(q0*q0 + q1*q1 + q2*q2 + q3*q3);
    float qw = q0*rn, qx = q1*rn, qy = q2*rn, qz = q3*rn;
    float r00 = 1.0f-2.0f*(qy*qy+qz*qz), r01 = 2.0f*(qx*qy-qz*qw), r02 = 2.0f*(qx*qz+qy*qw);
    float r10 = 2.0f*(qx*qy+qz*qw), r11 = 1.0f-2.0f*(qx*qx+qz*qz), r12 = 2.0f*(qy*qz-qx*qw);
    float r20 = 2.0f*(qx*qz-qy*qw), r21 = 2.0f*(qy*qz+qx*qw), r22 = 1.0f-2.0f*(qx*qx+qy*qy);
    float tx = tvec[pose*3+0], ty = tvec[pose*3+1], tz = tvec[pose*3+2];

    // ---- per-slab gaussian params, staged once (512 g, 1/thread) ----
    if (tid < SLAB) {
        int g = split*SLAB + tid;
        float p0 = gpos[g*3+0], p1 = gpos[g*3+1], p2 = gpos[g*3+2];
        float cxm = r00*p0 + r01*p1 + r02*p2 + tx;
        float cym = r10*p0 + r11*p1 + r12*p2 + ty;
        float czm = r20*p0 + r21*p1 + r22*p2 + tz;
        float iz  = 1.0f / czm;
        u_s[tid] = cxm*iz*FX_C + CX_C;
        v_s[tid] = cym*iz*FY_C + CY_C;
        float s  = gscl[g];
        ke_s[tid] = NEG_HALF_LOG2E / (s*s);
        float og = gopa[g];
        wc_s[0][tid] = og * gcol[g*3+0];
        wc_s[1][tid] = og * gcol[g*3+1];
        wc_s[2][tid] = og * gcol[g*3+2];
        wc_s[3][tid] = og;
    }
    __syncthreads();

    const int lane = tid & 63;
    const int wave = tid >> 6;            // 0..15
    const int wm   = wave >> 3;           // m band: [wm*64, wm*64+64)
    const int wn8  = wave & 7;            // n band: [wn8*64, wn8*64+64)

    // staging roles per K=32 chunk:
    //   threads 0..511   stage B: 4g x 2x x 4c  (8 exps)
    //   threads 512..1023 stage A: 4g x 2y      (8 exps)
    const bool isB = (tid < 512);
    const int st   = tid & 511;
    const int g4   = (st & 7) << 2;       // 0,4,..,28
    const int rg   = st >> 3;             // 0..63 -> rows rg*2, rg*2+1

    // MFMA frag addressing (verified 16x16x32 bf16 layouts)
    const int frow = lane & 15;
    const int kq   = (lane >> 4) << 3;    // k = quad*8 + j

    f32x4 acc[4][4] = {};  // [mt][nt]: m = wm*64+mt*16+quad*4+r, n = wn8*64+nt*16+(lane&15)

    // ---- staging macro body, chunk ch -> buffer b ----
#define STAGE_CHUNK(ch, b)                                                     \
    {                                                                          \
        const int gb = ((ch) << 5) + g4;                                       \
        const float4 kv = *(const float4*)&ke_s[gb];                           \
        if (isB) {                                                             \
            const float4 uv = *(const float4*)&u_s[gb];                        \
            float e[2][4];                                                     \
            _Pragma("unroll")                                                  \
            for (int xi = 0; xi < 2; ++xi) {                                   \
                const float xf = (float)(rg*2 + xi);                           \
                float d;                                                       \
                d = xf - uv.x; e[xi][0] = EXP2(kv.x*d*d);                      \
                d = xf - uv.y; e[xi][1] = EXP2(kv.y*d*d);                      \
                d = xf - uv.z; e[xi][2] = EXP2(kv.z*d*d);                      \
                d = xf - uv.w; e[xi][3] = EXP2(kv.w*d*d);                      \
            }                                                                  \
            _Pragma("unroll")                                                  \
            for (int c = 0; c < 4; ++c) {                                      \
                const float4 wv = *(const float4*)&wc_s[c][gb];                \
                _Pragma("unroll")                                              \
                for (int xi = 0; xi < 2; ++xi) {                               \
                    uint2 pk;                                                  \
                    pk.x = bfpk2(e[xi][0]*wv.x, e[xi][1]*wv.y);                \
                    pk.y = bfpk2(e[xi][2]*wv.z, e[xi][3]*wv.w);                \
                    *(uint2*)&B_lds[b][(c << 7) + rg*2 + xi][g4] = pk;         \
                }                                                              \
            }                                                                  \
        } else {                                                               \
            const float4 vv = *(const float4*)&v_s[gb];                        \
            _Pragma("unroll")                                                  \
            for (int yi = 0; yi < 2; ++yi) {                                   \
                const float yf = (float)(rg*2 + yi);                           \
                float d, f0, f1, f2, f3;                                       \
                d = yf - vv.x; f0 = EXP2(kv.x*d*d);                            \
                d = yf - vv.y; f1 = EXP2(kv.y*d*d);                            \
                d = yf - vv.z; f2 = EXP2(kv.z*d*d);                            \
                d = yf - vv.w; f3 = EXP2(kv.w*d*d);                            \
                uint2 pk;                                                      \
                pk.x = bfpk2(f0, f1); pk.y = bfpk2(f2, f3);                    \
                *(uint2*)&A_lds[b][rg*2 + yi][g4] = pk;                        \
            }                                                                  \
        }                                                                      \
    }

    // ---- MFMA macro body, chunk from buffer cb (K=32, one step) ----
#define MFMA_CHUNK(cb)                                                         \
    {                                                                          \
        short8 a[4], b[4];                                                     \
        _Pragma("unroll")                                                      \
        for (int mt = 0; mt < 4; ++mt)                                         \
            a[mt] = *(const short8*)&A_lds[cb][wm*64 + mt*16 + frow][kq];      \
        _Pragma("unroll")                                                      \
        for (int nt = 0; nt < 4; ++nt)                                         \
            b[nt] = *(const short8*)&B_lds[cb][wn8*64 + nt*16 + frow][kq];     \
        _Pragma("unroll")                                                      \
        for (int mt = 0; mt < 4; ++mt)                                         \
            _Pragma("unroll")                                                  \
            for (int nt = 0; nt < 4; ++nt)                                     \
                acc[mt][nt] = __builtin_amdgcn_mfma_f32_16x16x32_bf16(         \
                    a[mt], b[nt], acc[mt][nt], 0, 0, 0);                       \
    }

    // prologue: stage chunk 0 into buffer 0
    STAGE_CHUNK(0, 0)

    for (int ch = 0; ch < NCH; ++ch) {
        __syncthreads();   // chunk ch fully staged; all reads of buf (ch+1)&1 drained
        const int cb = ch & 1;
        if (isB) {
            // B-staging waves (0-7): stage next, then MFMA current
            if (ch + 1 < NCH) { STAGE_CHUNK(ch + 1, (ch + 1) & 1) }
            MFMA_CHUNK(cb)
        } else {
            // A-staging waves (8-15): MFMA current first, then stage next
            MFMA_CHUNK(cb)
            if (ch + 1 < NCH) { STAGE_CHUNK(ch + 1, (ch + 1) & 1) }
        }
    }
#undef STAGE_CHUNK
#undef MFMA_CHUNK

    // ---- epilogue: every wave stores its [64m x 64n] tile ----
    const int q4 = (lane >> 4) << 2;          // 0,4,8,12
    const int n0 = wn8*64 + (lane & 15);
    if (STORE) {
        ushort* bp = pbuf + ((size_t)(pose*KSPLIT + split) * H_IMG + wm*64) * 512 + n0;
        #pragma unroll
        for (int mt = 0; mt < 4; ++mt)
            #pragma unroll
            for (int nt = 0; nt < 4; ++nt)
                #pragma unroll
                for (int r = 0; r < 4; ++r)
                    bp[(size_t)(mt*16 + q4 + r)*512 + nt*16] = bf16u(acc[mt][nt][r]);
    } else {
        float* bp = accum + ((size_t)(pose*H_IMG + wm*64) * 512) + n0;
        #pragma unroll
        for (int mt = 0; mt < 4; ++mt)
            #pragma unroll
            for (int nt = 0; nt < 4; ++nt)
                #pragma unroll
                for (int r = 0; r < 4; ++r)
                    atomicAdd(bp + (size_t)(mt*16 + q4 + r)*512 + nt*16, acc[mt][nt][r]);
    }
}

// STORE path: sum the 128 bf16 split partials, normalize, tiled output.
// grid 256 = (pose, y); 1024 threads = (split-group sg 0..15, n-octet ng 0..63).
__global__ __launch_bounds__(1024) void reduce_norm_kernel(
    const ushort* __restrict__ pbuf, float* __restrict__ out)
{
    __shared__ float red[16][512];       // 32 KB
    __shared__ float tot[512];
    const int b  = blockIdx.x;
    const int p  = b >> 7;
    const int y  = b & 127;
    const int t  = threadIdx.x;
    const int sg = t >> 6;               // 0..15: splits [sg*8, sg*8+8)
    const int ng = t & 63;               // n octet: n = ng*8 .. ng*8+7

    const uint4* base = (const uint4*)(pbuf +
        ((size_t)(p*KSPLIT + sg*8) * H_IMG + y) * 512 + ng*8);
    float s[8] = {};
    #pragma unroll
    for (int i = 0; i < 8; ++i) {
        uint4 v = base[(size_t)i * (H_IMG*512/8)];
        s[0] += __uint_as_float(v.x << 16);
        s[1] += __uint_as_float(v.x & 0xFFFF0000u);
        s[2] += __uint_as_float(v.y << 16);
        s[3] += __uint_as_float(v.y & 0xFFFF0000u);
        s[4] += __uint_as_float(v.z << 16);
        s[5] += __uint_as_float(v.z & 0xFFFF0000u);
        s[6] += __uint_as_float(v.w << 16);
        s[7] += __uint_as_float(v.w & 0xFFFF0000u);
    }
    #pragma unroll
    for (int j = 0; j < 8; ++j) red[sg][ng*8 + j] = s[j];
    __syncthreads();

    if (t < 512) {
        float acc = 0.0f;
        #pragma unroll
        for (int g = 0; g < 16; ++g) acc += red[g][t];
        tot[t] = acc;
    }
    __syncthreads();

    if (t < 384) {
        const int c = t >> 7, x = t & 127;
        float inv = 1.0f / (tot[384 + x] + EPS_TOT);
        // output: [pose*16 + tile][3][32][32], tile = y>>3, q = (y&7)*128 + x
        int tt = y >> 3;
        int q  = ((y & 7) << 7) + x;
        out[(size_t)((p*16 + tt)*3 + c) * 1024 + q] = tot[t] * inv;
    }
}

// ATOMIC fallback: img = num/(den+eps), tiled output layout.
__global__ void normalize_kernel(const float* __restrict__ acc, float* __restrict__ out) {
    int idx = blockIdx.x * 256 + threadIdx.x;   // 0..32767 : (pose, y, x)
    int x = idx & 127;
    int y = (idx >> 7) & 127;
    int p = idx >> 14;
    const float* base = acc + (size_t)(p*128 + y) * 512;
    float inv = 1.0f / (base[384 + x] + EPS_TOT);
    int t = y >> 3;
    int q = ((y & 7) << 7) + x;
    float* ob = out + (size_t)((p*16 + t)*3) * 1024 + q;
    ob[0]    = base[x]       * inv;
    ob[1024] = base[128 + x] * inv;
    ob[2048] = base[256 + x] * inv;
}

extern "C" void kernel_launch(void* const* d_in, const int* in_sizes, int n_in,
                              void* d_out, int out_size, void* d_ws, size_t ws_size,
                              hipStream_t stream) {
    const float* gpos = (const float*)d_in[0];   // [65536,3]
    const float* gcol = (const float*)d_in[1];   // [65536,3]
    const float* gopa = (const float*)d_in[2];   // [65536,1]
    const float* gscl = (const float*)d_in[3];   // [65536,1]
    const float* qv   = (const float*)d_in[4];   // [2,4]
    const float* tv   = (const float*)d_in[5];   // [2,3]
    float* out = (float*)d_out;                  // [32,3,32,32] fp32

    // bf16 partials: 2 poses * 128 splits * 128 y * 512 n * 2B = 33,554,432 B
    const size_t need = (size_t)2 * KSPLIT * H_IMG * 512 * sizeof(ushort);

    if (ws_size >= need) {
        ushort* pbuf = (ushort*)d_ws;
        render_kernel<true><<<dim3(KSPLIT, 2), dim3(1024), 0, stream>>>(
            gpos, gcol, gopa, gscl, qv, tv, nullptr, pbuf);
        reduce_norm_kernel<<<dim3(256), dim3(1024), 0, stream>>>(pbuf, out);
    } else {
        float* acc = (float*)d_ws;               // 512 KB fp32 accumulator
        zero_accum_kernel<<<dim3(512), dim3(256), 0, stream>>>(acc);
        render_kernel<false><<<dim3(KSPLIT, 2), dim3(1024), 0, stream>>>(
            gpos, gcol, gopa, gscl, qv, tv, acc, nullptr);
        normalize_kernel<<<dim3(128), dim3(256), 0, stream>>>(acc, out);
    }
}